// Round 5
// baseline (157.341 us; speedup 1.0000x reference)
//
#include <hip/hip_runtime.h>
#include <stdint.h>

// Problem constants (from reference)
#define S 7
#define BB 2
#define CLS 20
#define NCHUNK (8192 * S * S / 64)   // 6272 chunks of 64 cells
#define CPB 64                       // cells per chunk == threads per block (1 wave)
#define THREADS 64
#define GRID 1568                    // 6272 / 4 -> exactly 4 chunks per block
#define NCH 4
#define PRED_F 30                    // BB*5 + CLS
#define TGT_F 25                     // CLS + 5

// Async 16B-per-lane global->LDS copy. LDS dest = wave-uniform base + lane*16.
#define ASYNC_CP16(gsrc, ldst)                                                  \
    __builtin_amdgcn_global_load_lds(                                           \
        (const __attribute__((address_space(1))) void*)(gsrc),                  \
        (__attribute__((address_space(3))) void*)(ldst), 16, 0, 0)

// gfx9 waitcnt imm: vmcnt[3:0]@[3:0], expcnt@[6:4], lgkmcnt@[11:8], vmcnt[5:4]@[15:14]
#define WAIT_VM15()  __builtin_amdgcn_s_waitcnt(0x0F7F)  // vmcnt(15), others free
#define WAIT_VM0()   __builtin_amdgcn_s_waitcnt(0x0F70)  // vmcnt(0),  others free
#define WAIT_LGKM0() __builtin_amdgcn_s_waitcnt(0xC07F)  // lgkmcnt(0), others free

__device__ __forceinline__ float iou_fn(float ax, float ay, float aw, float ah,
                                        float bx, float by, float bw, float bh) {
    float ax1 = ax - aw * 0.5f, ay1 = ay - ah * 0.5f;
    float ax2 = ax + aw * 0.5f, ay2 = ay + ah * 0.5f;
    float bx1 = bx - bw * 0.5f, by1 = by - bh * 0.5f;
    float bx2 = bx + bw * 0.5f, by2 = by + bh * 0.5f;
    float iw = fmaxf(fminf(ax2, bx2) - fmaxf(ax1, bx1), 0.0f);
    float ih = fmaxf(fminf(ay2, by2) - fmaxf(ay1, by1), 0.0f);
    float inter = iw * ih;
    float uni = fabsf(aw * ah) + fabsf(bw * bh) - inter;
    return inter / (uni + 1e-6f);
}

// Issue one chunk's staging: 15 global_load_lds dwordx4 ops (8 pred + 7 tgt).
__device__ __forceinline__ void prefetch_chunk(const float* __restrict__ pred,
                                               const float* __restrict__ tgt,
                                               int c, float* lpb, float* ltb, int t) {
    // pred chunk: 7680 B = 7 full 1024B wave-rounds + 512B tail (lanes 0..31)
    const float* gp = pred + (size_t)c * (CPB * PRED_F) + t * 4;
    #pragma unroll
    for (int i = 0; i < 7; ++i) ASYNC_CP16(gp + i * 256, lpb + i * 256);
    if (t < 32) ASYNC_CP16(gp + 7 * 256, lpb + 7 * 256);
    // tgt chunk: 6400 B = 6 full 1024B wave-rounds + 256B tail (lanes 0..15)
    const float* gt = tgt + (size_t)c * (CPB * TGT_F) + t * 4;
    #pragma unroll
    for (int i = 0; i < 6; ++i) ASYNC_CP16(gt + i * 256, ltb + i * 256);
    if (t < 16) ASYNC_CP16(gt + 6 * 256, ltb + 6 * 256);
}

// Single fused kernel: persistent-style single-wave blocks, double-buffered async
// LDS staging, exactly 4 chunks per block. Last block (GRID-1, dispatched last)
// spin-waits on per-block done flags and performs the final reduction -> d_out.
// Flags use agent-scope release/acquire atomics: release flushes the writer's
// partials past its XCD L2; acquire-bypass loads dodge stale poison lines in the
// finisher's own XCD L2 (per-XCD L2s are not cross-coherent).
__global__ __launch_bounds__(THREADS) void yolo_fused(const float* __restrict__ pred,
                                                      const float* __restrict__ tgt,
                                                      float* __restrict__ pl,
                                                      float* __restrict__ pi,
                                                      float* __restrict__ po,
                                                      uint32_t* __restrict__ flags,
                                                      float* __restrict__ out) {
    __shared__ float lp[2][CPB * PRED_F];   // 2 x 7680 B
    __shared__ float lt[2][CPB * TGT_F];    // 2 x 6400 B

    const int b = blockIdx.x;
    const int t = threadIdx.x;              // == lane (single wave)

    prefetch_chunk(pred, tgt, b, lp[0], lt[0], t);
    prefetch_chunk(pred, tgt, b + GRID, lp[1], lt[1], t);

    float accL = 0.f, accI = 0.f, accO = 0.f;

    #pragma unroll
    for (int k = 0; k < NCH; ++k) {
        // Newer chunk's 15 loads stay outstanding while we consume the older one.
        if (k + 1 < NCH) WAIT_VM15();
        else             WAIT_VM0();

        const float* pp = lp[k & 1] + t * PRED_F;
        const float* tp = lt[k & 1] + t * TGT_F;

        float tconf = tp[CLS + 0];
        float tx = tp[CLS + 1], ty = tp[CLS + 2], tw = tp[CLS + 3], th = tp[CLS + 4];

        float iou0 = iou_fn(pp[CLS + 1], pp[CLS + 2], pp[CLS + 3], pp[CLS + 4], tx, ty, tw, th);
        float iou1 = iou_fn(pp[CLS + 6], pp[CLS + 7], pp[CLS + 8], pp[CLS + 9], tx, ty, tw, th);
        // jnp.argmax takes FIRST max on ties -> box 1 only on strict greater
        int sel = (iou1 > iou0) ? 1 : 0;
        float iou_best = fmaxf(iou0, iou1);

        const float* pb = pp + CLS + sel * 5;
        float dx = tx - pb[1], dy = ty - pb[2];
        float center = dx * dx + dy * dy;
        float dw = sqrtf(tw) - sqrtf(fabsf(pb[3]));
        float dh = sqrtf(th) - sqrtf(fabsf(pb[4]));
        float wh = dw * dw + dh * dh;
        float dc = tconf - pb[0];
        float conf_sq = dc * dc;

        float cls_sq = 0.0f;
        #pragma unroll
        for (int j = 0; j < CLS; ++j) {
            float d = pp[j] - tp[j];
            cls_sq += d * d;
        }

        float objf = (tconf == 1.0f) ? 1.0f : 0.0f;
        accL += objf * (5.0f * (center + wh) + conf_sq + cls_sq)
              + (1.0f - objf) * 0.5f * conf_sq;
        accI += objf * iou_best;
        accO += objf;

        // Refill the buffer just consumed with chunk k+2 (if it exists).
        if (k + 2 < NCH) {
            WAIT_LGKM0();   // all ds_reads of this buffer retired before DMA overwrite
            prefetch_chunk(pred, tgt, b + (k + 2) * GRID, lp[k & 1], lt[k & 1], t);
        }
    }

    // One 64-lane shuffle reduction, then publish partial + done flag.
    #pragma unroll
    for (int off = 32; off > 0; off >>= 1) {
        accL += __shfl_down(accL, off, 64);
        accI += __shfl_down(accI, off, 64);
        accO += __shfl_down(accO, off, 64);
    }
    if (t == 0) {
        pl[b] = accL;
        pi[b] = accI;
        po[b] = accO;
        // Release: prior partial stores become agent-visible before the flag.
        __hip_atomic_store(&flags[b], 1u, __ATOMIC_RELEASE, __HIP_MEMORY_SCOPE_AGENT);
    }

    // Last-dispatched block finishes the reduction once all flags are set.
    if (b == GRID - 1) {
        float L = 0.f, I = 0.f, O = 0.f;
        for (int k = t; k < GRID; k += 64) {
            while (__hip_atomic_load(&flags[k], __ATOMIC_ACQUIRE,
                                     __HIP_MEMORY_SCOPE_AGENT) != 1u) {
                __builtin_amdgcn_s_sleep(2);
            }
            L += __hip_atomic_load(&pl[k], __ATOMIC_RELAXED, __HIP_MEMORY_SCOPE_AGENT);
            I += __hip_atomic_load(&pi[k], __ATOMIC_RELAXED, __HIP_MEMORY_SCOPE_AGENT);
            O += __hip_atomic_load(&po[k], __ATOMIC_RELAXED, __HIP_MEMORY_SCOPE_AGENT);
        }
        #pragma unroll
        for (int off = 32; off > 0; off >>= 1) {
            L += __shfl_down(L, off, 64);
            I += __shfl_down(I, off, 64);
            O += __shfl_down(O, off, 64);
        }
        if (t == 0) {
            out[0] = L;
            out[1] = I / fmaxf(O, 1.0f);
        }
    }
}

extern "C" void kernel_launch(void* const* d_in, const int* in_sizes, int n_in,
                              void* d_out, int out_size, void* d_ws, size_t ws_size,
                              hipStream_t stream) {
    const float* pred = (const float*)d_in[0];
    const float* tgt  = (const float*)d_in[1];
    float* out = (float*)d_out;

    // Workspace layout: 3 partial arrays + flag array (all fully rewritten each call;
    // flag test is ==1u, robust to 0xAA poison or zero init).
    float* pl = (float*)d_ws;
    float* pi = pl + GRID;
    float* po = pi + GRID;
    uint32_t* flags = (uint32_t*)(po + GRID);

    yolo_fused<<<GRID, THREADS, 0, stream>>>(pred, tgt, pl, pi, po, flags, out);
}

// Round 6
// 104.224 us; speedup vs baseline: 1.5096x; 1.5096x over previous
//
#include <hip/hip_runtime.h>
#include <stdint.h>

// Problem constants (from reference)
#define S 7
#define BB 2
#define CLS 20
#define NCELLS (8192 * S * S)        // 401408
#define CPB 64                       // cells per block == threads per block (1 wave)
#define THREADS 64
#define NBLK (NCELLS / CPB)          // 6272
#define PRED_F 30                    // BB*5 + CLS
#define TGT_F 25                     // CLS + 5

// Async 16B-per-lane global->LDS copy. LDS dest = wave-uniform base + lane*16.
#define ASYNC_CP16(gsrc, ldst)                                                  \
    __builtin_amdgcn_global_load_lds(                                           \
        (const __attribute__((address_space(1))) void*)(gsrc),                  \
        (__attribute__((address_space(3))) void*)(ldst), 16, 0, 0)

__device__ __forceinline__ float iou_fn(float ax, float ay, float aw, float ah,
                                        float bx, float by, float bw, float bh) {
    float ax1 = ax - aw * 0.5f, ay1 = ay - ah * 0.5f;
    float ax2 = ax + aw * 0.5f, ay2 = ay + ah * 0.5f;
    float bx1 = bx - bw * 0.5f, by1 = by - bh * 0.5f;
    float bx2 = bx + bw * 0.5f, by2 = by + bh * 0.5f;
    float iw = fmaxf(fminf(ax2, bx2) - fmaxf(ax1, bx1), 0.0f);
    float ih = fmaxf(fminf(ay2, by2) - fmaxf(ay1, by1), 0.0f);
    float inter = iw * ih;
    float uni = fabsf(aw * ah) + fabsf(bw * bh) - inter;
    return inter / (uni + 1e-6f);
}

// R3 structure (best measured): one wave per block, ~11 blocks/CU (14.08 KB LDS),
// async global->LDS staging (no VGPR round-trip), one float4 partial per block.
// NOTE (R5 pitfall): do NOT fuse the final reduction via agent-scope flag
// atomics — on CDNA4 agent-scope release/acquire compile to L2 writeback/
// invalidate per op; the spin loop's repeated invalidates cost ~50 µs and
// wreck input locality for co-resident blocks (measured R5: 107->157 µs).
__global__ __launch_bounds__(THREADS) void yolo_main(const float* __restrict__ pred,
                                                     const float* __restrict__ tgt,
                                                     float4* __restrict__ part) {
    __shared__ float lp[CPB * PRED_F];   // 7680 B = 1920 floats
    __shared__ float lt[CPB * TGT_F];    // 6400 B = 1600 floats

    const int b = blockIdx.x;
    const int t = threadIdx.x;           // == lane (single wave)

    // pred chunk: 7680 B = 7 full 1024B wave-rounds + 512B tail (lanes 0..31)
    const float* gp = pred + (size_t)b * (CPB * PRED_F) + t * 4;  // per-lane 16B slot
    #pragma unroll
    for (int i = 0; i < 7; ++i) {
        ASYNC_CP16(gp + i * 256, lp + i * 256);
    }
    if (t < 32) {
        ASYNC_CP16(gp + 7 * 256, lp + 7 * 256);
    }
    // tgt chunk: 6400 B = 6 full 1024B wave-rounds + 256B tail (lanes 0..15)
    const float* gt = tgt + (size_t)b * (CPB * TGT_F) + t * 4;
    #pragma unroll
    for (int i = 0; i < 6; ++i) {
        ASYNC_CP16(gt + i * 256, lt + i * 256);
    }
    if (t < 16) {
        ASYNC_CP16(gt + 6 * 256, lt + 6 * 256);
    }
    __syncthreads();   // drains vmcnt (global_load_lds) before LDS reads

    const float* pp = lp + t * PRED_F;
    const float* tp = lt + t * TGT_F;

    float tconf = tp[CLS + 0];
    float tx = tp[CLS + 1], ty = tp[CLS + 2], tw = tp[CLS + 3], th = tp[CLS + 4];

    float iou0 = iou_fn(pp[CLS + 1], pp[CLS + 2], pp[CLS + 3], pp[CLS + 4], tx, ty, tw, th);
    float iou1 = iou_fn(pp[CLS + 6], pp[CLS + 7], pp[CLS + 8], pp[CLS + 9], tx, ty, tw, th);
    // jnp.argmax takes FIRST max on ties -> box 1 only on strict greater
    int sel = (iou1 > iou0) ? 1 : 0;
    float iou_best = fmaxf(iou0, iou1);

    const float* pb = pp + CLS + sel * 5;
    float dx = tx - pb[1], dy = ty - pb[2];
    float center = dx * dx + dy * dy;
    float dw = sqrtf(tw) - sqrtf(fabsf(pb[3]));
    float dh = sqrtf(th) - sqrtf(fabsf(pb[4]));
    float wh = dw * dw + dh * dh;
    float dc = tconf - pb[0];
    float conf_sq = dc * dc;

    float cls_sq = 0.0f;
    #pragma unroll
    for (int k = 0; k < CLS; ++k) {
        float d = pp[k] - tp[k];
        cls_sq += d * d;
    }

    float objf = (tconf == 1.0f) ? 1.0f : 0.0f;
    float loss = objf * (5.0f * (center + wh) + conf_sq + cls_sq)
               + (1.0f - objf) * 0.5f * conf_sq;
    float iou_o = objf * iou_best;

    // 64-lane shuffle reduction, then ONE float4 partial store per block.
    #pragma unroll
    for (int off = 32; off > 0; off >>= 1) {
        loss  += __shfl_down(loss,  off, 64);
        iou_o += __shfl_down(iou_o, off, 64);
        objf  += __shfl_down(objf,  off, 64);
    }
    if (t == 0) {
        part[b] = make_float4(loss, iou_o, objf, 0.0f);
    }
}

__global__ __launch_bounds__(1024) void yolo_fin(const float4* __restrict__ part,
                                                 float* __restrict__ out) {
    __shared__ float red[3][1024 / 64];
    float l = 0.f, i = 0.f, o = 0.f;
    for (int k = threadIdx.x; k < NBLK; k += 1024) {   // ~6 coalesced float4 iters
        float4 v = part[k];
        l += v.x;
        i += v.y;
        o += v.z;
    }
    #pragma unroll
    for (int off = 32; off > 0; off >>= 1) {
        l += __shfl_down(l, off, 64);
        i += __shfl_down(i, off, 64);
        o += __shfl_down(o, off, 64);
    }
    const int wave = threadIdx.x >> 6, lane = threadIdx.x & 63;
    if (lane == 0) {
        red[0][wave] = l;
        red[1][wave] = i;
        red[2][wave] = o;
    }
    __syncthreads();
    if (threadIdx.x == 0) {
        float L = 0.f, I = 0.f, O = 0.f;
        #pragma unroll
        for (int w = 0; w < 1024 / 64; ++w) {
            L += red[0][w];
            I += red[1][w];
            O += red[2][w];
        }
        out[0] = L;
        out[1] = I / fmaxf(O, 1.0f);
    }
}

extern "C" void kernel_launch(void* const* d_in, const int* in_sizes, int n_in,
                              void* d_out, int out_size, void* d_ws, size_t ws_size,
                              hipStream_t stream) {
    const float* pred = (const float*)d_in[0];
    const float* tgt  = (const float*)d_in[1];
    float* out = (float*)d_out;
    float4* part = (float4*)d_ws;   // NBLK float4 partials = 100 KB (fully overwritten)

    yolo_main<<<NBLK, THREADS, 0, stream>>>(pred, tgt, part);
    yolo_fin<<<1, 1024, 0, stream>>>(part, out);
}